// Round 16
// baseline (569.799 us; speedup 1.0000x reference)
//
#include <hip/hip_runtime.h>
#include <cstdint>
#include <cmath>

using u16 = unsigned short;
typedef __attribute__((ext_vector_type(8))) short  short8;
typedef __attribute__((ext_vector_type(4))) float  f32x4;

// ---------------- problem constants ----------------
constexpr int NR   = 32768;
constexpr int N0I  = 32,  N1I = 16;
constexpr int N0H  = 128, N1H = 64, STP = 192;
constexpr int P00_1 = 528, P11_1 = 136, P0_1 = 664;
constexpr int P1_1  = 512;
constexpr int P00_2 = 8256, P11_2 = 2080, P0_2 = 10336;
constexpr int P1_2  = 8192;
constexpr int NCH_SS = P00_2 / 32;   // 258
constexpr int NCH    = P0_2 / 32;    // 323
constexpr int NCH1   = P1_2 / 32;    // 256
constexpr int NCH_L1 = 21;
constexpr int NCH_V1 = P1_1 / 32;    // 16

constexpr float INV_SQRT3 = 0.57735026918962576f;

// ---------------- workspace layout (bytes) ----------------
constexpr size_t O_MSS2 = 0;
constexpr size_t O_MDD2 = O_MSS2 + (size_t)P00_2 * 2;
constexpr size_t O_MC1  = O_MDD2 + (size_t)P11_2 * 2;
constexpr size_t O_W01F = 22528;
constexpr size_t O_W11F = O_W01F + (size_t)NCH_L1 * 12 * 1024 * 2;
constexpr size_t O_W0F  = O_W11F + (size_t)NCH_V1 * 4 * 1024 * 2;
constexpr size_t O_W1F  = O_W0F + (size_t)NCH * 12 * 1024 * 2;
constexpr size_t O_WFM  = O_W1F + (size_t)NCH1 * 4 * 1024 * 2;
constexpr size_t O_WFD  = O_WFM + (size_t)32 * 1024 * 2;
constexpr size_t O_S1   = O_WFD + (size_t)8 * 1024 * 2;
constexpr size_t O_V1   = O_S1 + (size_t)NR * N0H * 4;
constexpr size_t O_S2   = O_V1 + (size_t)NR * (N1H * 3) * 4;
constexpr size_t O_G1   = O_S2;
constexpr size_t O_G2   = O_S2 + (size_t)NR * N0H * 4;
constexpr size_t O_V2   = O_G2 + (size_t)NR * N1H * 4;
constexpr size_t WS_NEED = O_V2 + (size_t)NR * (N1H * 3) * 4;

// ---------------- helpers ----------------
__device__ __forceinline__ unsigned short f2bf(float x) {
  unsigned u = __float_as_uint(x);
  u += 0x7fffu + ((u >> 16) & 1u);
  return (unsigned short)(u >> 16);
}
__device__ __forceinline__ float bf2f(unsigned short h) {
  return __uint_as_float(((unsigned)h) << 16);
}
__device__ __forceinline__ unsigned cvt_pk_bf16(float lo, float hi) {
  unsigned r;
  asm("v_cvt_pk_bf16_f32 %0, %1, %2" : "=v"(r) : "v"(lo), "v"(hi));
  return r;
}

// ---------------- map init ----------------
__global__ void k_init_maps(u16* mss2, u16* mdd2, u16* mc1) {
  const int t = threadIdx.x;
  if (t < N0H) { int u = t, base = u*N0H - u*(u-1)/2;
    for (int v = u; v < N0H; ++v) mss2[base + v - u] = (u16)((u<<8)|v); }
  if (t < N1H) { int u = t, base = u*N1H - u*(u-1)/2;
    for (int v = u; v < N1H; ++v) mdd2[base + v - u] = (u16)((u<<8)|v); }
  if (t < N0I) { int u = t, base = u*N0I - u*(u-1)/2;
    for (int v = u; v < N0I; ++v) mc1[base + v - u] = (u16)((u<<8)|v); }
  if (t < N1I) { int u = t, base = u*N1I - u*(u-1)/2;
    for (int v = u; v < N1I; ++v) mc1[P00_1 + base + v - u] = (u16)(0x8000 | (u<<8) | v); }
  if (t < 8) mc1[P0_1 + t] = 0xFFFF;
}

// ---------------- prep kernels (validated) ----------------
__global__ __launch_bounds__(256) void k_prep_b(const float* __restrict__ w0_2, short* __restrict__ w0f) {
  const int g = blockIdx.x * 4 + (threadIdx.x >> 6);
  const int lane = threadIdx.x & 63;
  if (g >= NCH * 12) return;
  const int c = g / 12, nf = g - c * 12;
  const int k = c * 32 + (lane >> 4) * 8;
  const int n = nf * 16 + (lane & 15);
  const float* src = &w0_2[(size_t)n * P0_2 + k];
  float4 f0 = *(const float4*)src;
  float4 f1 = *(const float4*)(src + 4);
  const float v[8] = {f0.x, f0.y, f0.z, f0.w, f1.x, f1.y, f1.z, f1.w};
  short8 h, l;
  #pragma unroll
  for (int j = 0; j < 8; ++j) {
    unsigned short hh = f2bf(v[j]);
    h[j] = (short)hh;
    l[j] = (short)f2bf(v[j] - bf2f(hh));
  }
  short* dst = w0f + (size_t)g * 1024 + lane * 8;
  *(short8*)dst = h;
  *(short8*)(dst + 512) = l;
}

__global__ __launch_bounds__(256) void k_prep_b1v(const float* __restrict__ w1_2, short* __restrict__ w1f) {
  const int g = blockIdx.x * 4 + (threadIdx.x >> 6);
  const int lane = threadIdx.x & 63;
  if (g >= NCH1 * 4) return;
  const int c = g >> 2, nf = g & 3;
  const int k = c * 32 + (lane >> 4) * 8;
  const int n = nf * 16 + (lane & 15);
  const float* src = &w1_2[(size_t)n * P1_2 + k];
  float4 f0 = *(const float4*)src;
  float4 f1 = *(const float4*)(src + 4);
  const float v[8] = {f0.x, f0.y, f0.z, f0.w, f1.x, f1.y, f1.z, f1.w};
  short8 h, l;
  #pragma unroll
  for (int j = 0; j < 8; ++j) {
    unsigned short hh = f2bf(v[j]);
    h[j] = (short)hh;
    l[j] = (short)f2bf(v[j] - bf2f(hh));
  }
  short* dst = w1f + (size_t)g * 1024 + lane * 8;
  *(short8*)dst = h;
  *(short8*)(dst + 512) = l;
}

__global__ __launch_bounds__(256) void k_prep_b01(const float* __restrict__ w0_1, short* __restrict__ w01f) {
  const int g = blockIdx.x * 4 + (threadIdx.x >> 6);
  const int lane = threadIdx.x & 63;
  if (g >= NCH_L1 * 12) return;
  const int c = g / 12, nf = g - c * 12;
  const int k = c * 32 + (lane >> 4) * 8;
  const int n = nf * 16 + (lane & 15);
  short8 h, l;
  if (k + 8 <= P0_1) {
    const float* src = &w0_1[(size_t)n * P0_1 + k];
    float4 f0 = *(const float4*)src;
    float4 f1 = *(const float4*)(src + 4);
    const float v[8] = {f0.x, f0.y, f0.z, f0.w, f1.x, f1.y, f1.z, f1.w};
    #pragma unroll
    for (int j = 0; j < 8; ++j) {
      unsigned short hh = f2bf(v[j]);
      h[j] = (short)hh;
      l[j] = (short)f2bf(v[j] - bf2f(hh));
    }
  } else {
    #pragma unroll
    for (int j = 0; j < 8; ++j) { h[j] = 0; l[j] = 0; }
  }
  short* dst = w01f + (size_t)g * 1024 + lane * 8;
  *(short8*)dst = h;
  *(short8*)(dst + 512) = l;
}

__global__ __launch_bounds__(256) void k_prep_b11(const float* __restrict__ w1_1, short* __restrict__ w11f) {
  const int g = blockIdx.x * 4 + (threadIdx.x >> 6);
  const int lane = threadIdx.x & 63;
  if (g >= NCH_V1 * 4) return;
  const int c = g >> 2, nf = g & 3;
  const int k = c * 32 + (lane >> 4) * 8;
  const int n = nf * 16 + (lane & 15);
  const float* src = &w1_1[(size_t)n * P1_1 + k];
  float4 f0 = *(const float4*)src;
  float4 f1 = *(const float4*)(src + 4);
  const float v[8] = {f0.x, f0.y, f0.z, f0.w, f1.x, f1.y, f1.z, f1.w};
  short8 h, l;
  #pragma unroll
  for (int j = 0; j < 8; ++j) {
    unsigned short hh = f2bf(v[j]);
    h[j] = (short)hh;
    l[j] = (short)f2bf(v[j] - bf2f(hh));
  }
  short* dst = w11f + (size_t)g * 1024 + lane * 8;
  *(short8*)dst = h;
  *(short8*)(dst + 512) = l;
}

// ---------------- prep: symmetric final matrices (validated R12) ----------------
__global__ __launch_bounds__(256) void k_prep_wfm(const float* __restrict__ wf, short* __restrict__ wfm) {
  const int g = blockIdx.x * 4 + (threadIdx.x >> 6);
  const int lane = threadIdx.x & 63;
  if (g >= 32) return;
  const int c = g >> 3, nf = g & 7;
  const int k0 = c * 32 + (lane >> 4) * 8;
  const int n = nf * 16 + (lane & 15);
  short8 h, l;
  #pragma unroll
  for (int j = 0; j < 8; ++j) {
    const int k = k0 + j;
    const int u = k < n ? k : n, v = k < n ? n : k;
    float val = wf[u*N0H - u*(u-1)/2 + (v - u)];
    if (k != n) val *= 0.5f;
    unsigned short hh = f2bf(val);
    h[j] = (short)hh;
    l[j] = (short)f2bf(val - bf2f(hh));
  }
  short* dst = wfm + (size_t)g * 1024 + lane * 8;
  *(short8*)dst = h;
  *(short8*)(dst + 512) = l;
}
__global__ __launch_bounds__(256) void k_prep_wfd(const float* __restrict__ wf, short* __restrict__ wfd) {
  const int g = blockIdx.x * 4 + (threadIdx.x >> 6);
  const int lane = threadIdx.x & 63;
  if (g >= 8) return;
  const int c = g >> 2, nf = g & 3;
  const int k0 = c * 32 + (lane >> 4) * 8;
  const int n = nf * 16 + (lane & 15);
  short8 h, l;
  #pragma unroll
  for (int j = 0; j < 8; ++j) {
    const int k = k0 + j;
    const int u = k < n ? k : n, v = k < n ? n : k;
    float val = wf[P00_2 + u*N1H - u*(u-1)/2 + (v - u)] * INV_SQRT3;
    if (k != n) val *= 0.5f;
    unsigned short hh = f2bf(val);
    h[j] = (short)hh;
    l[j] = (short)f2bf(val - bf2f(hh));
  }
  short* dst = wfd + (size_t)g * 1024 + lane * 8;
  *(short8*)dst = h;
  *(short8*)(dst + 512) = l;
}

// ---------------- layer 1 scalar path (validated R9) ----------------
__global__ __launch_bounds__(256) void k_layer1s_mfma(
    const float* __restrict__ x,
    const short* __restrict__ w01f,
    const u16* __restrict__ mc1,
    float* __restrict__ s1, float* __restrict__ g1)
{
  __shared__ float sS[64*33];
  __shared__ float sV[64*49];
  __shared__ __align__(16) short sA[2][2048];

  const int tid  = threadIdx.x;
  const int lane = tid & 63, wid = tid >> 6;
  const int wm = wid & 1, wn = wid >> 1;
  const int r0 = blockIdx.x * 64;
  const int kp = tid & 15, rg = tid >> 4;

  for (int i = tid; i < 64*80; i += 256) {
    int r = i / 80, c = i - r*80;
    float val = x[(size_t)(r0 + r)*80 + c];
    if (c < N0I) sS[r*33 + c] = val;
    else         sV[r*49 + (c - N0I)] = val;
  }

  f32x4 acc[2][6];
  #pragma unroll
  for (int mi = 0; mi < 2; ++mi)
    #pragma unroll
    for (int q = 0; q < 6; ++q) acc[mi][q] = {0.f, 0.f, 0.f, 0.f};

  auto evalf = [&](unsigned mv, int m) -> float {
    if (mv == 0xFFFFu) return 0.f;
    const int u = (mv >> 8) & 0x7F, v = mv & 255;
    if (mv & 0x8000u) {
      const float* pa = &sV[m*49 + u*3];
      const float* pb = &sV[m*49 + v*3];
      return (pa[0]*pb[0] + pa[1]*pb[1] + pa[2]*pb[2]) * INV_SQRT3;
    }
    return sS[m*33 + u] * sS[m*33 + v];
  };

  auto write_feats = [&](int buf, int c) {
    const unsigned mv2 = *(const unsigned*)(mc1 + c*32 + 2*kp);
    const unsigned m0 = mv2 & 0xFFFFu, m1 = mv2 >> 16;
    char* a0 = (char*)&sA[buf][0];
    #pragma unroll
    for (int i = 0; i < 4; ++i) {
      const int m = rg*4 + i;
      float f0 = evalf(m0, m);
      float f1 = evalf(m1, m);
      const int off = m*64 + (((kp>>2) ^ ((m>>1)&3)) << 4) + ((kp&3) << 2);
      *(unsigned*)(a0 + off) = cvt_pk_bf16(f0, f1);
    }
  };

  auto mfma_step = [&](int c, int buf) {
    const short* bb = w01f + ((size_t)c * 12 + wn * 6) * 1024 + lane * 8;
    short8 bh[6], bl[6];
    #pragma unroll
    for (int q = 0; q < 6; ++q) {
      bh[q] = *(const short8*)(bb + q*1024);
      bl[q] = *(const short8*)(bb + q*1024 + 512);
    }
    #pragma unroll
    for (int mi = 0; mi < 2; ++mi) {
      const int m = (wm*2 + mi)*16 + (lane & 15);
      const int kg = lane >> 4;
      const int off = m*64 + ((kg ^ ((m>>1)&3)) << 4);
      short8 ah = *(const short8*)((const char*)&sA[buf][0] + off);
      #pragma unroll
      for (int q = 0; q < 6; ++q) {
        acc[mi][q] = __builtin_amdgcn_mfma_f32_16x16x32_bf16(ah, bh[q], acc[mi][q], 0, 0, 0);
        acc[mi][q] = __builtin_amdgcn_mfma_f32_16x16x32_bf16(ah, bl[q], acc[mi][q], 0, 0, 0);
      }
    }
  };

  __syncthreads();
  write_feats(0, 0);
  __syncthreads();
  for (int c = 0; c < NCH_L1; ++c) {
    const int buf = c & 1;
    if (c < NCH_L1 - 1) write_feats(buf ^ 1, c + 1);
    mfma_step(c, buf);
    __syncthreads();
  }

  const float nrm = 1.0f / sqrtf((float)P0_1);
  #pragma unroll
  for (int mi = 0; mi < 2; ++mi) {
    const int rowbase = r0 + (wm*2 + mi)*16 + (lane >> 4)*4;
    #pragma unroll
    for (int q = 0; q < 6; ++q) {
      const int col = (wn*6 + q)*16 + (lane & 15);
      #pragma unroll
      for (int r = 0; r < 4; ++r) {
        float val = acc[mi][q][r] * nrm;
        float sg = 1.f / (1.f + __expf(-val));
        if (col < N0H) s1[(size_t)(rowbase + r)*N0H + col] = val * sg;
        else           g1[(size_t)(rowbase + r)*N1H + (col - N0H)] = sg;
      }
    }
  }
}

// ---------------- layer 1 vector path (validated R9) ----------------
__global__ __launch_bounds__(256) void k_layer1v_f(
    const float* __restrict__ x,
    const short* __restrict__ w11f,
    const float* __restrict__ g1,
    float* __restrict__ v1)
{
  __shared__ float sS[32*33];
  __shared__ float sV[32*49];
  __shared__ float sG[32*66];
  __shared__ __align__(16) short sA[2][3072];

  const int tid = threadIdx.x, lane = tid & 63, wid = tid >> 6;
  const int wm = wid & 1, wn = wid >> 1;
  const int n0 = blockIdx.x * 32;
  const int kp = tid & 15, rg = tid >> 4;

  for (int i = tid; i < 32*80; i += 256) {
    int n = i / 80, c = i - n*80;
    float val = x[(size_t)(n0 + n)*80 + c];
    if (c < N0I) sS[n*33 + c] = val;
    else         sV[n*49 + (c - N0I)] = val;
  }
  for (int i = tid; i < 32*64; i += 256) {
    int n = i >> 6, c = i & 63;
    sG[n*66 + c] = g1[(size_t)(n0 + n)*64 + c];
  }

  f32x4 acc[3][2];
  #pragma unroll
  for (int mi = 0; mi < 3; ++mi)
    #pragma unroll
    for (int q = 0; q < 2; ++q) acc[mi][q] = {0.f, 0.f, 0.f, 0.f};

  auto gen = [&](int buf, int c) {
    const int u = c*2 + (kp >> 3);
    const int w0 = (2*kp) & 15;
    char* a0 = (char*)&sA[buf][0];
    #pragma unroll
    for (int rr = 0; rr < 6; ++rr) {
      const int row = rg*6 + rr;
      const int n = rg*2 + rr/3, i3 = rr % 3;
      const float sval = sS[n*33 + u];
      const float f0 = sval * sV[n*49 + w0*3 + i3];
      const float f1 = sval * sV[n*49 + (w0+1)*3 + i3];
      const int off = row*64 + (((kp>>2) ^ ((row>>1)&3)) << 4) + ((kp&3) << 2);
      *(unsigned*)(a0 + off) = cvt_pk_bf16(f0, f1);
    }
  };

  auto mfma_step = [&](int c, int buf) {
    const short* bb = w11f + ((size_t)c * 4 + wn * 2) * 1024 + lane * 8;
    short8 bh[2], bl[2];
    #pragma unroll
    for (int q = 0; q < 2; ++q) {
      bh[q] = *(const short8*)(bb + q*1024);
      bl[q] = *(const short8*)(bb + q*1024 + 512);
    }
    const int c15 = lane & 15, kg = lane >> 4;
    #pragma unroll
    for (int mi = 0; mi < 3; ++mi) {
      const int row = (wm*3 + mi)*16 + c15;
      const int off = row*64 + ((kg ^ ((row>>1)&3)) << 4);
      short8 ah = *(const short8*)((const char*)&sA[buf][0] + off);
      #pragma unroll
      for (int q = 0; q < 2; ++q) {
        acc[mi][q] = __builtin_amdgcn_mfma_f32_16x16x32_bf16(ah, bh[q], acc[mi][q], 0, 0, 0);
        acc[mi][q] = __builtin_amdgcn_mfma_f32_16x16x32_bf16(ah, bl[q], acc[mi][q], 0, 0, 0);
      }
    }
  };

  __syncthreads();
  gen(0, 0);
  __syncthreads();
  for (int c = 0; c < NCH_V1; ++c) {
    const int buf = c & 1;
    if (c < NCH_V1 - 1) gen(buf ^ 1, c + 1);
    mfma_step(c, buf);
    __syncthreads();
  }

  const float nrm = 1.0f / sqrtf((float)P1_1);
  const int c15 = lane & 15, lg = lane >> 4;
  #pragma unroll
  for (int mi = 0; mi < 3; ++mi) {
    #pragma unroll
    for (int q = 0; q < 2; ++q) {
      const int m = (wn*2 + q)*16 + c15;
      #pragma unroll
      for (int r = 0; r < 4; ++r) {
        const int row = (wm*3 + mi)*16 + lg*4 + r;
        const int n = row / 3, i3 = row - n*3;
        const float g = sG[n*66 + m] * nrm;
        v1[(size_t)(n0 + n)*192 + m*3 + i3] = acc[mi][q][r] * g;
      }
    }
  }
}

// ---------------- layer 2 scalar path: R12 structure + stride-80 sA (bank-conflict fix) ----------------
struct B3 { short8 b0, b1, b2; };

__global__ __launch_bounds__(256, 5) void k_l2_scalar_mfma(
    const float* __restrict__ s1, const float* __restrict__ v1,
    const short* __restrict__ w0f,
    const u16* __restrict__ mss, const u16* __restrict__ mdd,
    float* __restrict__ s2, float* __restrict__ g2)
{
  __shared__ float sSV[32*193];
  __shared__ __align__(16) short sA[2][1280];   // 32 rows x 80B

  const int tid  = threadIdx.x;
  const int lane = tid & 63, wid = tid >> 6;
  const int wn = wid;
  const int r0 = blockIdx.x * 32;

  const int kp = tid & 15;
  const int rg = tid >> 4;

  for (int i = tid; i < 32*128; i += 256) {
    int r = i >> 7, c = i & 127;
    sSV[r*129 + c] = s1[(size_t)(r0 + r)*N0H + c];
  }

  f32x4 acc[2][3];
  #pragma unroll
  for (int mi = 0; mi < 2; ++mi)
    #pragma unroll
    for (int q = 0; q < 3; ++q) acc[mi][q] = {0.f, 0.f, 0.f, 0.f};

  auto loadB = [&](int c) -> B3 {
    const short* bb = w0f + ((size_t)c * 12 + wn * 3) * 1024 + lane * 8;
    B3 b;
    b.b0 = *(const short8*)(bb);
    b.b1 = *(const short8*)(bb + 1024);
    b.b2 = *(const short8*)(bb + 2048);
    return b;
  };

  auto write_feats_ss = [&](int buf, int c) {
    const unsigned mv = *(const unsigned*)(mss + c*32 + 2*kp);
    const int u0 = (mv >> 8) & 255,  v0 = mv & 255;
    const int u1 = (mv >> 24) & 255, v1i = (mv >> 16) & 255;
    char* a0 = (char*)&sA[buf][0];
    #pragma unroll
    for (int i = 0; i < 2; ++i) {
      const int m = rg*2 + i;
      const float* sr = &sSV[m*129];
      float f0 = sr[u0] * sr[v0];
      float f1 = sr[u1] * sr[v1i];
      const int off = m*80 + (((kp>>2) ^ ((m>>1)&3)) << 4) + ((kp&3) << 2);
      *(unsigned*)(a0 + off) = cvt_pk_bf16(f0, f1);
    }
  };
  auto write_feats_dd = [&](int buf, int c) {
    const unsigned mv = *(const unsigned*)(mdd + (c - NCH_SS)*32 + 2*kp);
    const int u0 = (mv >> 8) & 255,  v0 = mv & 255;
    const int u1 = (mv >> 24) & 255, v1i = (mv >> 16) & 255;
    char* a0 = (char*)&sA[buf][0];
    #pragma unroll
    for (int i = 0; i < 2; ++i) {
      const int m = rg*2 + i;
      const float* vr = &sSV[m*193];
      const float* pa0 = vr + u0*3; const float* pb0 = vr + v0*3;
      const float* pa1 = vr + u1*3; const float* pb1 = vr + v1i*3;
      float f0 = (pa0[0]*pb0[0] + pa0[1]*pb0[1] + pa0[2]*pb0[2]) * INV_SQRT3;
      float f1 = (pa1[0]*pb1[0] + pa1[1]*pb1[1] + pa1[2]*pb1[2]) * INV_SQRT3;
      const int off = m*80 + (((kp>>2) ^ ((m>>1)&3)) << 4) + ((kp&3) << 2);
      *(unsigned*)(a0 + off) = cvt_pk_bf16(f0, f1);
    }
  };

  auto mfma_step = [&](const B3& B, int buf) {
    #pragma unroll
    for (int mi = 0; mi < 2; ++mi) {
      const int m = mi*16 + (lane & 15);
      const int kg = lane >> 4;
      const int off = m*80 + ((kg ^ ((m>>1)&3)) << 4);
      short8 ah = *(const short8*)((const char*)&sA[buf][0] + off);
      acc[mi][0] = __builtin_amdgcn_mfma_f32_16x16x32_bf16(ah, B.b0, acc[mi][0], 0, 0, 0);
      acc[mi][1] = __builtin_amdgcn_mfma_f32_16x16x32_bf16(ah, B.b1, acc[mi][1], 0, 0, 0);
      acc[mi][2] = __builtin_amdgcn_mfma_f32_16x16x32_bf16(ah, B.b2, acc[mi][2], 0, 0, 0);
    }
  };

  __syncthreads();

  B3 Ba = loadB(0), Bb;
  write_feats_ss(0, 0);
  __syncthreads();
  for (int c = 0; c < NCH_SS; c += 2) {
    Bb = loadB(c + 1);
    write_feats_ss(1, c + 1);
    mfma_step(Ba, 0);
    __syncthreads();
    if (c + 2 < NCH_SS) { Ba = loadB(c + 2); write_feats_ss(0, c + 2); }
    mfma_step(Bb, 1);
    __syncthreads();
  }

  for (int i = tid; i < 32*192; i += 256) {
    int r = i / 192, c = i - r*192;
    sSV[r*193 + c] = v1[(size_t)(r0 + r)*192 + c];
  }
  __syncthreads();

  Ba = loadB(NCH_SS);
  write_feats_dd(0, NCH_SS);
  __syncthreads();
  for (int c = NCH_SS; c < NCH; c += 2) {
    const bool has1 = (c + 1 < NCH);
    if (has1) { Bb = loadB(c + 1); write_feats_dd(1, c + 1); }
    mfma_step(Ba, 0);
    __syncthreads();
    if (has1) {
      if (c + 2 < NCH) { Ba = loadB(c + 2); write_feats_dd(0, c + 2); }
      mfma_step(Bb, 1);
      __syncthreads();
    }
  }

  const float nrm = 1.0f / sqrtf((float)P0_2);
  #pragma unroll
  for (int mi = 0; mi < 2; ++mi) {
    const int rowbase = r0 + mi*16 + (lane >> 4)*4;
    #pragma unroll
    for (int q = 0; q < 3; ++q) {
      const int col = (wn*3 + q)*16 + (lane & 15);
      #pragma unroll
      for (int r = 0; r < 4; ++r) {
        float val = acc[mi][q][r] * nrm;
        float sg = 1.f / (1.f + __expf(-val));
        if (col < N0H) s2[(size_t)(rowbase + r)*N0H + col] = val * sg;
        else           g2[(size_t)(rowbase + r)*N1H + (col - N0H)] = sg;
      }
    }
  }
}

// ---------------- layer 2 vector path: R12 structure + stride-80 sA ----------------
__global__ __launch_bounds__(256, 5) void k_l2_vector_f(
    const float* __restrict__ s1, const float* __restrict__ v1,
    const short* __restrict__ w1f,
    const float* __restrict__ g2,
    float* __restrict__ v2)
{
  __shared__ float sS[16*129];
  __shared__ float sV[16*193];
  __shared__ float sG[16*66];
  __shared__ __align__(16) short sA[2][1920];   // 48 rows x 80B

  const int tid = threadIdx.x, lane = tid & 63, wid = tid >> 6;
  const int wn = wid;
  const int n0 = blockIdx.x * 16;
  const int kp = tid & 15, rg = tid >> 4;

  for (int i = tid; i < 16*128; i += 256) {
    int n = i >> 7, c = i & 127;
    sS[n*129 + c] = s1[(size_t)(n0 + n)*128 + c];
  }
  for (int i = tid; i < 16*192; i += 256) {
    int n = i / 192, c = i - n*192;
    sV[n*193 + c] = v1[(size_t)(n0 + n)*192 + c];
  }
  for (int i = tid; i < 16*64; i += 256) {
    int n = i >> 6, c = i & 63;
    sG[n*66 + c] = g2[(size_t)(n0 + n)*64 + c];
  }

  f32x4 acc[3];
  #pragma unroll
  for (int mi = 0; mi < 3; ++mi) acc[mi] = {0.f, 0.f, 0.f, 0.f};

  auto loadB = [&](int c) -> short8 {
    return *(const short8*)(w1f + ((size_t)c * 4 + wn) * 1024 + lane * 8);
  };

  auto gen = [&](int buf, int c) {
    const int u = c >> 1;
    const int w0 = (c & 1) * 32 + 2*kp;
    char* a0 = (char*)&sA[buf][0];
    const float sval = sS[rg*129 + u];
    #pragma unroll
    for (int i3 = 0; i3 < 3; ++i3) {
      const int row = rg*3 + i3;
      const float f0 = sval * sV[rg*193 + w0*3 + i3];
      const float f1 = sval * sV[rg*193 + (w0+1)*3 + i3];
      const int off = row*80 + (((kp>>2) ^ ((row>>1)&3)) << 4) + ((kp&3) << 2);
      *(unsigned*)(a0 + off) = cvt_pk_bf16(f0, f1);
    }
  };

  auto mfma_step = [&](short8 bh, int buf) {
    const int c15 = lane & 15, kg = lane >> 4;
    #pragma unroll
    for (int mi = 0; mi < 3; ++mi) {
      const int row = mi*16 + c15;
      const int off = row*80 + ((kg ^ ((row>>1)&3)) << 4);
      short8 ah = *(const short8*)((const char*)&sA[buf][0] + off);
      acc[mi] = __builtin_amdgcn_mfma_f32_16x16x32_bf16(ah, bh, acc[mi], 0, 0, 0);
    }
  };

  __syncthreads();
  short8 Ba = loadB(0), Bb;
  gen(0, 0);
  __syncthreads();
  for (int c = 0; c < NCH1; c += 2) {
    Bb = loadB(c + 1);
    gen(1, c + 1);
    mfma_step(Ba, 0);
    __syncthreads();
    if (c + 2 < NCH1) { Ba = loadB(c + 2); gen(0, c + 2); }
    mfma_step(Bb, 1);
    __syncthreads();
  }

  const float nrm = 1.0f / sqrtf((float)P1_2);
  const int c15 = lane & 15, lg = lane >> 4;
  #pragma unroll
  for (int mi = 0; mi < 3; ++mi) {
    const int m = wn*16 + c15;
    #pragma unroll
    for (int r = 0; r < 4; ++r) {
      const int row = mi*16 + lg*4 + r;
      const int n = row / 3, i3 = row - n*3;
      const float g = sG[n*66 + m] * nrm;
      v2[(size_t)(n0 + n)*192 + m*3 + i3] = acc[mi][r] * g;
    }
  }
}

// ---------------- final (validated R12) ----------------
__global__ __launch_bounds__(256) void k_final_mfma(
    const float* __restrict__ s2, const float* __restrict__ v2,
    const short* __restrict__ wfm, const short* __restrict__ wfd,
    float* __restrict__ out)
{
  __shared__ float sS2[32*129];
  __shared__ float sV2[32*193];
  __shared__ __align__(16) short sAS[4][1024];
  __shared__ __align__(16) short sAD[2][3072];
  __shared__ float psumS[32][5];
  __shared__ float psumD[96][5];

  const int tid = threadIdx.x, lane = tid & 63, wid = tid >> 6;
  const int n0 = blockIdx.x * 32;
  const int kp = tid & 15, rg = tid >> 4;
  const int c15 = lane & 15, lg = lane >> 4;

  for (int i = tid; i < 32*128; i += 256) {
    int n = i >> 7, c = i & 127;
    sS2[n*129 + c] = s2[(size_t)(n0 + n)*128 + c];
  }
  for (int i = tid; i < 32*192; i += 256) {
    int n = i / 192, c = i - n*192;
    sV2[n*193 + c] = v2[(size_t)(n0 + n)*192 + c];
  }
  __syncthreads();

  #pragma unroll
  for (int c = 0; c < 4; ++c) {
    char* a0 = (char*)&sAS[c][0];
    #pragma unroll
    for (int i = 0; i < 2; ++i) {
      const int m = rg*2 + i;
      float f0 = sS2[m*129 + c*32 + 2*kp];
      float f1 = sS2[m*129 + c*32 + 2*kp + 1];
      const int off = m*64 + (((kp>>2) ^ ((m>>1)&3)) << 4) + ((kp&3) << 2);
      *(unsigned*)(a0 + off) = cvt_pk_bf16(f0, f1);
    }
  }
  #pragma unroll
  for (int c = 0; c < 2; ++c) {
    char* a0 = (char*)&sAD[c][0];
    #pragma unroll
    for (int rr = 0; rr < 6; ++rr) {
      const int row = rg*6 + rr;
      const int n = rg*2 + rr/3, i3 = rr % 3;
      const int w0 = c*32 + 2*kp;
      float f0 = sV2[n*193 + w0*3 + i3];
      float f1 = sV2[n*193 + (w0+1)*3 + i3];
      const int off = row*64 + (((kp>>2) ^ ((row>>1)&3)) << 4) + ((kp&3) << 2);
      *(unsigned*)(a0 + off) = cvt_pk_bf16(f0, f1);
    }
  }
  __syncthreads();

  f32x4 accS[2][2];
  #pragma unroll
  for (int mi = 0; mi < 2; ++mi)
    #pragma unroll
    for (int q = 0; q < 2; ++q) accS[mi][q] = {0.f, 0.f, 0.f, 0.f};
  #pragma unroll
  for (int c = 0; c < 4; ++c) {
    #pragma unroll
    for (int q = 0; q < 2; ++q) {
      const short* bb = wfm + ((size_t)(c*8 + wid*2 + q))*1024 + lane*8;
      short8 bh = *(const short8*)(bb);
      short8 bl = *(const short8*)(bb + 512);
      #pragma unroll
      for (int mi = 0; mi < 2; ++mi) {
        const int row = mi*16 + c15;
        const int off = row*64 + ((lg ^ ((row>>1)&3)) << 4);
        short8 ah = *(const short8*)((const char*)&sAS[c][0] + off);
        accS[mi][q] = __builtin_amdgcn_mfma_f32_16x16x32_bf16(ah, bh, accS[mi][q], 0, 0, 0);
        accS[mi][q] = __builtin_amdgcn_mfma_f32_16x16x32_bf16(ah, bl, accS[mi][q], 0, 0, 0);
      }
    }
  }

  f32x4 accD[6];
  #pragma unroll
  for (int mi = 0; mi < 6; ++mi) accD[mi] = {0.f, 0.f, 0.f, 0.f};
  #pragma unroll
  for (int c = 0; c < 2; ++c) {
    const short* bb = wfd + ((size_t)(c*4 + wid))*1024 + lane*8;
    short8 bh = *(const short8*)(bb);
    short8 bl = *(const short8*)(bb + 512);
    #pragma unroll
    for (int mi = 0; mi < 6; ++mi) {
      const int row = mi*16 + c15;
      const int off = row*64 + ((lg ^ ((row>>1)&3)) << 4);
      short8 ah = *(const short8*)((const char*)&sAD[c][0] + off);
      accD[mi] = __builtin_amdgcn_mfma_f32_16x16x32_bf16(ah, bh, accD[mi], 0, 0, 0);
      accD[mi] = __builtin_amdgcn_mfma_f32_16x16x32_bf16(ah, bl, accD[mi], 0, 0, 0);
    }
  }

  #pragma unroll
  for (int mi = 0; mi < 2; ++mi) {
    #pragma unroll
    for (int r = 0; r < 4; ++r) {
      const int row = mi*16 + lg*4 + r;
      float p = 0.f;
      #pragma unroll
      for (int q = 0; q < 2; ++q) {
        const int col = (wid*2 + q)*16 + c15;
        p += accS[mi][q][r] * sS2[row*129 + col];
      }
      #pragma unroll
      for (int off = 1; off < 16; off <<= 1) p += __shfl_xor(p, off, 16);
      if (c15 == 0) psumS[row][wid] = p;
    }
  }
  #pragma unroll
  for (int mi = 0; mi < 6; ++mi) {
    #pragma unroll
    for (int r = 0; r < 4; ++r) {
      const int row = mi*16 + lg*4 + r;
      const int n = row / 3, i3 = row - n*3;
      const int col = wid*16 + c15;
      float p = accD[mi][r] * sV2[n*193 + col*3 + i3];
      #pragma unroll
      for (int off = 1; off < 16; off <<= 1) p += __shfl_xor(p, off, 16);
      if (c15 == 0) psumD[row][wid] = p;
    }
  }
  __syncthreads();

  if (tid < 32) {
    float s = 0.f;
    #pragma unroll
    for (int w = 0; w < 4; ++w) s += psumS[tid][w];
    #pragma unroll
    for (int j = 0; j < 3; ++j)
      #pragma unroll
      for (int w = 0; w < 4; ++w) s += psumD[tid*3 + j][w];
    out[n0 + tid] = s * (1.0f / sqrtf((float)P0_2));
  }
}

// ---------------- launch ----------------
extern "C" void kernel_launch(void* const* d_in, const int* in_sizes, int n_in,
                              void* d_out, int out_size, void* d_ws, size_t ws_size,
                              hipStream_t stream)
{
  const float* x    = (const float*)d_in[0];
  const float* w0_1 = (const float*)d_in[1];
  const float* w1_1 = (const float*)d_in[2];
  const float* w0_2 = (const float*)d_in[3];
  const float* w1_2 = (const float*)d_in[4];
  const float* w0_f = (const float*)d_in[5];
  float* out = (float*)d_out;
  char* ws = (char*)d_ws;

  if (ws_size < WS_NEED) return;

  u16* mss2 = (u16*)(ws + O_MSS2);
  u16* mdd2 = (u16*)(ws + O_MDD2);
  u16* mc1  = (u16*)(ws + O_MC1);
  short* w01f = (short*)(ws + O_W01F);
  short* w11f = (short*)(ws + O_W11F);
  short* w0f  = (short*)(ws + O_W0F);
  short* w1f  = (short*)(ws + O_W1F);
  short* wfm  = (short*)(ws + O_WFM);
  short* wfd  = (short*)(ws + O_WFD);
  float* s1 = (float*)(ws + O_S1);
  float* v1 = (float*)(ws + O_V1);
  float* s2 = (float*)(ws + O_S2);
  float* g1 = (float*)(ws + O_G1);
  float* g2 = (float*)(ws + O_G2);
  float* v2 = (float*)(ws + O_V2);

  hipLaunchKernelGGL(k_init_maps, dim3(1), dim3(128), 0, stream, mss2, mdd2, mc1);
  hipLaunchKernelGGL(k_prep_b01, dim3((NCH_L1*12 + 3)/4), dim3(256), 0, stream, w0_1, w01f);
  hipLaunchKernelGGL(k_prep_b11, dim3(NCH_V1), dim3(256), 0, stream, w1_1, w11f);
  hipLaunchKernelGGL(k_prep_b, dim3((NCH*12 + 3)/4), dim3(256), 0, stream, w0_2, w0f);
  hipLaunchKernelGGL(k_prep_b1v, dim3(NCH1), dim3(256), 0, stream, w1_2, w1f);
  hipLaunchKernelGGL(k_prep_wfm, dim3(8), dim3(256), 0, stream, w0_f, wfm);
  hipLaunchKernelGGL(k_prep_wfd, dim3(2), dim3(256), 0, stream, w0_f, wfd);
  hipLaunchKernelGGL(k_layer1s_mfma, dim3(NR/64), dim3(256), 0, stream,
                     x, w01f, mc1, s1, g1);
  hipLaunchKernelGGL(k_layer1v_f, dim3(NR/32), dim3(256), 0, stream,
                     x, w11f, g1, v1);
  hipLaunchKernelGGL(k_l2_scalar_mfma, dim3(NR/32), dim3(256), 0, stream,
                     s1, v1, w0f, mss2, mdd2, s2, g2);
  hipLaunchKernelGGL(k_l2_vector_f, dim3(NR/16), dim3(256), 0, stream,
                     s1, v1, w1f, g2, v2);
  hipLaunchKernelGGL(k_final_mfma, dim3(NR/32), dim3(256), 0, stream,
                     s2, v2, wfm, wfd, out);
}

// Round 17
// 508.321 us; speedup vs baseline: 1.1209x; 1.1209x over previous
//
#include <hip/hip_runtime.h>
#include <cstdint>
#include <cmath>

using u16 = unsigned short;
typedef __attribute__((ext_vector_type(8))) short  short8;
typedef __attribute__((ext_vector_type(4))) float  f32x4;

// ---------------- problem constants ----------------
constexpr int NR   = 32768;
constexpr int N0I  = 32,  N1I = 16;
constexpr int N0H  = 128, N1H = 64, STP = 192;
constexpr int P00_1 = 528, P11_1 = 136, P0_1 = 664;
constexpr int P1_1  = 512;
constexpr int P00_2 = 8256, P11_2 = 2080, P0_2 = 10336;
constexpr int P1_2  = 8192;
constexpr int NCH_SS = P00_2 / 32;   // 258
constexpr int NCH    = P0_2 / 32;    // 323
constexpr int NCH1   = P1_2 / 32;    // 256
constexpr int NCH_L1 = 21;
constexpr int NCH_V1 = P1_1 / 32;    // 16

constexpr float INV_SQRT3 = 0.57735026918962576f;

// ---------------- workspace layout (bytes) ----------------
constexpr size_t O_MSS2 = 0;
constexpr size_t O_MDD2 = O_MSS2 + (size_t)P00_2 * 2;
constexpr size_t O_MC1  = O_MDD2 + (size_t)P11_2 * 2;
constexpr size_t O_W01F = 22528;
constexpr size_t O_W11F = O_W01F + (size_t)NCH_L1 * 12 * 1024 * 2;
constexpr size_t O_W0F  = O_W11F + (size_t)NCH_V1 * 4 * 1024 * 2;
constexpr size_t O_W1F  = O_W0F + (size_t)NCH * 12 * 1024 * 2;
constexpr size_t O_WFM  = O_W1F + (size_t)NCH1 * 4 * 1024 * 2;
constexpr size_t O_WFD  = O_WFM + (size_t)32 * 1024 * 2;
constexpr size_t O_S1   = O_WFD + (size_t)8 * 1024 * 2;
constexpr size_t O_V1   = O_S1 + (size_t)NR * N0H * 4;
constexpr size_t O_S2   = O_V1 + (size_t)NR * (N1H * 3) * 4;
constexpr size_t O_G1   = O_S2;
constexpr size_t O_G2   = O_S2 + (size_t)NR * N0H * 4;
constexpr size_t O_V2   = O_G2 + (size_t)NR * N1H * 4;
constexpr size_t WS_NEED = O_V2 + (size_t)NR * (N1H * 3) * 4;

// ---------------- helpers ----------------
__device__ __forceinline__ unsigned short f2bf(float x) {
  unsigned u = __float_as_uint(x);
  u += 0x7fffu + ((u >> 16) & 1u);
  return (unsigned short)(u >> 16);
}
__device__ __forceinline__ float bf2f(unsigned short h) {
  return __uint_as_float(((unsigned)h) << 16);
}
__device__ __forceinline__ unsigned cvt_pk_bf16(float lo, float hi) {
  unsigned r;
  asm("v_cvt_pk_bf16_f32 %0, %1, %2" : "=v"(r) : "v"(lo), "v"(hi));
  return r;
}

// ---------------- map init ----------------
__global__ void k_init_maps(u16* mss2, u16* mdd2, u16* mc1) {
  const int t = threadIdx.x;
  if (t < N0H) { int u = t, base = u*N0H - u*(u-1)/2;
    for (int v = u; v < N0H; ++v) mss2[base + v - u] = (u16)((u<<8)|v); }
  if (t < N1H) { int u = t, base = u*N1H - u*(u-1)/2;
    for (int v = u; v < N1H; ++v) mdd2[base + v - u] = (u16)((u<<8)|v); }
  if (t < N0I) { int u = t, base = u*N0I - u*(u-1)/2;
    for (int v = u; v < N0I; ++v) mc1[base + v - u] = (u16)((u<<8)|v); }
  if (t < N1I) { int u = t, base = u*N1I - u*(u-1)/2;
    for (int v = u; v < N1I; ++v) mc1[P00_1 + base + v - u] = (u16)(0x8000 | (u<<8) | v); }
  if (t < 8) mc1[P0_1 + t] = 0xFFFF;
}

// ---------------- prep kernels (validated) ----------------
__global__ __launch_bounds__(256) void k_prep_b(const float* __restrict__ w0_2, short* __restrict__ w0f) {
  const int g = blockIdx.x * 4 + (threadIdx.x >> 6);
  const int lane = threadIdx.x & 63;
  if (g >= NCH * 12) return;
  const int c = g / 12, nf = g - c * 12;
  const int k = c * 32 + (lane >> 4) * 8;
  const int n = nf * 16 + (lane & 15);
  const float* src = &w0_2[(size_t)n * P0_2 + k];
  float4 f0 = *(const float4*)src;
  float4 f1 = *(const float4*)(src + 4);
  const float v[8] = {f0.x, f0.y, f0.z, f0.w, f1.x, f1.y, f1.z, f1.w};
  short8 h, l;
  #pragma unroll
  for (int j = 0; j < 8; ++j) {
    unsigned short hh = f2bf(v[j]);
    h[j] = (short)hh;
    l[j] = (short)f2bf(v[j] - bf2f(hh));
  }
  short* dst = w0f + (size_t)g * 1024 + lane * 8;
  *(short8*)dst = h;
  *(short8*)(dst + 512) = l;
}

__global__ __launch_bounds__(256) void k_prep_b1v(const float* __restrict__ w1_2, short* __restrict__ w1f) {
  const int g = blockIdx.x * 4 + (threadIdx.x >> 6);
  const int lane = threadIdx.x & 63;
  if (g >= NCH1 * 4) return;
  const int c = g >> 2, nf = g & 3;
  const int k = c * 32 + (lane >> 4) * 8;
  const int n = nf * 16 + (lane & 15);
  const float* src = &w1_2[(size_t)n * P1_2 + k];
  float4 f0 = *(const float4*)src;
  float4 f1 = *(const float4*)(src + 4);
  const float v[8] = {f0.x, f0.y, f0.z, f0.w, f1.x, f1.y, f1.z, f1.w};
  short8 h, l;
  #pragma unroll
  for (int j = 0; j < 8; ++j) {
    unsigned short hh = f2bf(v[j]);
    h[j] = (short)hh;
    l[j] = (short)f2bf(v[j] - bf2f(hh));
  }
  short* dst = w1f + (size_t)g * 1024 + lane * 8;
  *(short8*)dst = h;
  *(short8*)(dst + 512) = l;
}

__global__ __launch_bounds__(256) void k_prep_b01(const float* __restrict__ w0_1, short* __restrict__ w01f) {
  const int g = blockIdx.x * 4 + (threadIdx.x >> 6);
  const int lane = threadIdx.x & 63;
  if (g >= NCH_L1 * 12) return;
  const int c = g / 12, nf = g - c * 12;
  const int k = c * 32 + (lane >> 4) * 8;
  const int n = nf * 16 + (lane & 15);
  short8 h, l;
  if (k + 8 <= P0_1) {
    const float* src = &w0_1[(size_t)n * P0_1 + k];
    float4 f0 = *(const float4*)src;
    float4 f1 = *(const float4*)(src + 4);
    const float v[8] = {f0.x, f0.y, f0.z, f0.w, f1.x, f1.y, f1.z, f1.w};
    #pragma unroll
    for (int j = 0; j < 8; ++j) {
      unsigned short hh = f2bf(v[j]);
      h[j] = (short)hh;
      l[j] = (short)f2bf(v[j] - bf2f(hh));
    }
  } else {
    #pragma unroll
    for (int j = 0; j < 8; ++j) { h[j] = 0; l[j] = 0; }
  }
  short* dst = w01f + (size_t)g * 1024 + lane * 8;
  *(short8*)dst = h;
  *(short8*)(dst + 512) = l;
}

__global__ __launch_bounds__(256) void k_prep_b11(const float* __restrict__ w1_1, short* __restrict__ w11f) {
  const int g = blockIdx.x * 4 + (threadIdx.x >> 6);
  const int lane = threadIdx.x & 63;
  if (g >= NCH_V1 * 4) return;
  const int c = g >> 2, nf = g & 3;
  const int k = c * 32 + (lane >> 4) * 8;
  const int n = nf * 16 + (lane & 15);
  const float* src = &w1_1[(size_t)n * P1_1 + k];
  float4 f0 = *(const float4*)src;
  float4 f1 = *(const float4*)(src + 4);
  const float v[8] = {f0.x, f0.y, f0.z, f0.w, f1.x, f1.y, f1.z, f1.w};
  short8 h, l;
  #pragma unroll
  for (int j = 0; j < 8; ++j) {
    unsigned short hh = f2bf(v[j]);
    h[j] = (short)hh;
    l[j] = (short)f2bf(v[j] - bf2f(hh));
  }
  short* dst = w11f + (size_t)g * 1024 + lane * 8;
  *(short8*)dst = h;
  *(short8*)(dst + 512) = l;
}

// ---------------- prep: symmetric final matrices (validated R12) ----------------
__global__ __launch_bounds__(256) void k_prep_wfm(const float* __restrict__ wf, short* __restrict__ wfm) {
  const int g = blockIdx.x * 4 + (threadIdx.x >> 6);
  const int lane = threadIdx.x & 63;
  if (g >= 32) return;
  const int c = g >> 3, nf = g & 7;
  const int k0 = c * 32 + (lane >> 4) * 8;
  const int n = nf * 16 + (lane & 15);
  short8 h, l;
  #pragma unroll
  for (int j = 0; j < 8; ++j) {
    const int k = k0 + j;
    const int u = k < n ? k : n, v = k < n ? n : k;
    float val = wf[u*N0H - u*(u-1)/2 + (v - u)];
    if (k != n) val *= 0.5f;
    unsigned short hh = f2bf(val);
    h[j] = (short)hh;
    l[j] = (short)f2bf(val - bf2f(hh));
  }
  short* dst = wfm + (size_t)g * 1024 + lane * 8;
  *(short8*)dst = h;
  *(short8*)(dst + 512) = l;
}
__global__ __launch_bounds__(256) void k_prep_wfd(const float* __restrict__ wf, short* __restrict__ wfd) {
  const int g = blockIdx.x * 4 + (threadIdx.x >> 6);
  const int lane = threadIdx.x & 63;
  if (g >= 8) return;
  const int c = g >> 2, nf = g & 3;
  const int k0 = c * 32 + (lane >> 4) * 8;
  const int n = nf * 16 + (lane & 15);
  short8 h, l;
  #pragma unroll
  for (int j = 0; j < 8; ++j) {
    const int k = k0 + j;
    const int u = k < n ? k : n, v = k < n ? n : k;
    float val = wf[P00_2 + u*N1H - u*(u-1)/2 + (v - u)] * INV_SQRT3;
    if (k != n) val *= 0.5f;
    unsigned short hh = f2bf(val);
    h[j] = (short)hh;
    l[j] = (short)f2bf(val - bf2f(hh));
  }
  short* dst = wfd + (size_t)g * 1024 + lane * 8;
  *(short8*)dst = h;
  *(short8*)(dst + 512) = l;
}

// ---------------- layer 1 scalar path (validated R9) ----------------
__global__ __launch_bounds__(256) void k_layer1s_mfma(
    const float* __restrict__ x,
    const short* __restrict__ w01f,
    const u16* __restrict__ mc1,
    float* __restrict__ s1, float* __restrict__ g1)
{
  __shared__ float sS[64*33];
  __shared__ float sV[64*49];
  __shared__ __align__(16) short sA[2][2048];

  const int tid  = threadIdx.x;
  const int lane = tid & 63, wid = tid >> 6;
  const int wm = wid & 1, wn = wid >> 1;
  const int r0 = blockIdx.x * 64;
  const int kp = tid & 15, rg = tid >> 4;

  for (int i = tid; i < 64*80; i += 256) {
    int r = i / 80, c = i - r*80;
    float val = x[(size_t)(r0 + r)*80 + c];
    if (c < N0I) sS[r*33 + c] = val;
    else         sV[r*49 + (c - N0I)] = val;
  }

  f32x4 acc[2][6];
  #pragma unroll
  for (int mi = 0; mi < 2; ++mi)
    #pragma unroll
    for (int q = 0; q < 6; ++q) acc[mi][q] = {0.f, 0.f, 0.f, 0.f};

  auto evalf = [&](unsigned mv, int m) -> float {
    if (mv == 0xFFFFu) return 0.f;
    const int u = (mv >> 8) & 0x7F, v = mv & 255;
    if (mv & 0x8000u) {
      const float* pa = &sV[m*49 + u*3];
      const float* pb = &sV[m*49 + v*3];
      return (pa[0]*pb[0] + pa[1]*pb[1] + pa[2]*pb[2]) * INV_SQRT3;
    }
    return sS[m*33 + u] * sS[m*33 + v];
  };

  auto write_feats = [&](int buf, int c) {
    const unsigned mv2 = *(const unsigned*)(mc1 + c*32 + 2*kp);
    const unsigned m0 = mv2 & 0xFFFFu, m1 = mv2 >> 16;
    char* a0 = (char*)&sA[buf][0];
    #pragma unroll
    for (int i = 0; i < 4; ++i) {
      const int m = rg*4 + i;
      float f0 = evalf(m0, m);
      float f1 = evalf(m1, m);
      const int off = m*64 + (((kp>>2) ^ ((m>>1)&3)) << 4) + ((kp&3) << 2);
      *(unsigned*)(a0 + off) = cvt_pk_bf16(f0, f1);
    }
  };

  auto mfma_step = [&](int c, int buf) {
    const short* bb = w01f + ((size_t)c * 12 + wn * 6) * 1024 + lane * 8;
    short8 bh[6], bl[6];
    #pragma unroll
    for (int q = 0; q < 6; ++q) {
      bh[q] = *(const short8*)(bb + q*1024);
      bl[q] = *(const short8*)(bb + q*1024 + 512);
    }
    #pragma unroll
    for (int mi = 0; mi < 2; ++mi) {
      const int m = (wm*2 + mi)*16 + (lane & 15);
      const int kg = lane >> 4;
      const int off = m*64 + ((kg ^ ((m>>1)&3)) << 4);
      short8 ah = *(const short8*)((const char*)&sA[buf][0] + off);
      #pragma unroll
      for (int q = 0; q < 6; ++q) {
        acc[mi][q] = __builtin_amdgcn_mfma_f32_16x16x32_bf16(ah, bh[q], acc[mi][q], 0, 0, 0);
        acc[mi][q] = __builtin_amdgcn_mfma_f32_16x16x32_bf16(ah, bl[q], acc[mi][q], 0, 0, 0);
      }
    }
  };

  __syncthreads();
  write_feats(0, 0);
  __syncthreads();
  for (int c = 0; c < NCH_L1; ++c) {
    const int buf = c & 1;
    if (c < NCH_L1 - 1) write_feats(buf ^ 1, c + 1);
    mfma_step(c, buf);
    __syncthreads();
  }

  const float nrm = 1.0f / sqrtf((float)P0_1);
  #pragma unroll
  for (int mi = 0; mi < 2; ++mi) {
    const int rowbase = r0 + (wm*2 + mi)*16 + (lane >> 4)*4;
    #pragma unroll
    for (int q = 0; q < 6; ++q) {
      const int col = (wn*6 + q)*16 + (lane & 15);
      #pragma unroll
      for (int r = 0; r < 4; ++r) {
        float val = acc[mi][q][r] * nrm;
        float sg = 1.f / (1.f + __expf(-val));
        if (col < N0H) s1[(size_t)(rowbase + r)*N0H + col] = val * sg;
        else           g1[(size_t)(rowbase + r)*N1H + (col - N0H)] = sg;
      }
    }
  }
}

// ---------------- layer 1 vector path (validated R9) ----------------
__global__ __launch_bounds__(256) void k_layer1v_f(
    const float* __restrict__ x,
    const short* __restrict__ w11f,
    const float* __restrict__ g1,
    float* __restrict__ v1)
{
  __shared__ float sS[32*33];
  __shared__ float sV[32*49];
  __shared__ float sG[32*66];
  __shared__ __align__(16) short sA[2][3072];

  const int tid = threadIdx.x, lane = tid & 63, wid = tid >> 6;
  const int wm = wid & 1, wn = wid >> 1;
  const int n0 = blockIdx.x * 32;
  const int kp = tid & 15, rg = tid >> 4;

  for (int i = tid; i < 32*80; i += 256) {
    int n = i / 80, c = i - n*80;
    float val = x[(size_t)(n0 + n)*80 + c];
    if (c < N0I) sS[n*33 + c] = val;
    else         sV[n*49 + (c - N0I)] = val;
  }
  for (int i = tid; i < 32*64; i += 256) {
    int n = i >> 6, c = i & 63;
    sG[n*66 + c] = g1[(size_t)(n0 + n)*64 + c];
  }

  f32x4 acc[3][2];
  #pragma unroll
  for (int mi = 0; mi < 3; ++mi)
    #pragma unroll
    for (int q = 0; q < 2; ++q) acc[mi][q] = {0.f, 0.f, 0.f, 0.f};

  auto gen = [&](int buf, int c) {
    const int u = c*2 + (kp >> 3);
    const int w0 = (2*kp) & 15;
    char* a0 = (char*)&sA[buf][0];
    #pragma unroll
    for (int rr = 0; rr < 6; ++rr) {
      const int row = rg*6 + rr;
      const int n = rg*2 + rr/3, i3 = rr % 3;
      const float sval = sS[n*33 + u];
      const float f0 = sval * sV[n*49 + w0*3 + i3];
      const float f1 = sval * sV[n*49 + (w0+1)*3 + i3];
      const int off = row*64 + (((kp>>2) ^ ((row>>1)&3)) << 4) + ((kp&3) << 2);
      *(unsigned*)(a0 + off) = cvt_pk_bf16(f0, f1);
    }
  };

  auto mfma_step = [&](int c, int buf) {
    const short* bb = w11f + ((size_t)c * 4 + wn * 2) * 1024 + lane * 8;
    short8 bh[2], bl[2];
    #pragma unroll
    for (int q = 0; q < 2; ++q) {
      bh[q] = *(const short8*)(bb + q*1024);
      bl[q] = *(const short8*)(bb + q*1024 + 512);
    }
    const int c15 = lane & 15, kg = lane >> 4;
    #pragma unroll
    for (int mi = 0; mi < 3; ++mi) {
      const int row = (wm*3 + mi)*16 + c15;
      const int off = row*64 + ((kg ^ ((row>>1)&3)) << 4);
      short8 ah = *(const short8*)((const char*)&sA[buf][0] + off);
      #pragma unroll
      for (int q = 0; q < 2; ++q) {
        acc[mi][q] = __builtin_amdgcn_mfma_f32_16x16x32_bf16(ah, bh[q], acc[mi][q], 0, 0, 0);
        acc[mi][q] = __builtin_amdgcn_mfma_f32_16x16x32_bf16(ah, bl[q], acc[mi][q], 0, 0, 0);
      }
    }
  };

  __syncthreads();
  gen(0, 0);
  __syncthreads();
  for (int c = 0; c < NCH_V1; ++c) {
    const int buf = c & 1;
    if (c < NCH_V1 - 1) gen(buf ^ 1, c + 1);
    mfma_step(c, buf);
    __syncthreads();
  }

  const float nrm = 1.0f / sqrtf((float)P1_1);
  const int c15 = lane & 15, lg = lane >> 4;
  #pragma unroll
  for (int mi = 0; mi < 3; ++mi) {
    #pragma unroll
    for (int q = 0; q < 2; ++q) {
      const int m = (wn*2 + q)*16 + c15;
      #pragma unroll
      for (int r = 0; r < 4; ++r) {
        const int row = (wm*3 + mi)*16 + lg*4 + r;
        const int n = row / 3, i3 = row - n*3;
        const float g = sG[n*66 + m] * nrm;
        v1[(size_t)(n0 + n)*192 + m*3 + i3] = acc[mi][q][r] * g;
      }
    }
  }
}

// ---------------- layer 2 scalar path: M=32, B hi-only + VGPR-double-buffered B (R12) ----------------
struct B3 { short8 b0, b1, b2; };

__global__ __launch_bounds__(256, 5) void k_l2_scalar_mfma(
    const float* __restrict__ s1, const float* __restrict__ v1,
    const short* __restrict__ w0f,
    const u16* __restrict__ mss, const u16* __restrict__ mdd,
    float* __restrict__ s2, float* __restrict__ g2)
{
  __shared__ float sSV[32*193];
  __shared__ __align__(16) short sA[2][1024];

  const int tid  = threadIdx.x;
  const int lane = tid & 63, wid = tid >> 6;
  const int wn = wid;
  const int r0 = blockIdx.x * 32;

  const int kp = tid & 15;
  const int rg = tid >> 4;

  for (int i = tid; i < 32*128; i += 256) {
    int r = i >> 7, c = i & 127;
    sSV[r*129 + c] = s1[(size_t)(r0 + r)*N0H + c];
  }

  f32x4 acc[2][3];
  #pragma unroll
  for (int mi = 0; mi < 2; ++mi)
    #pragma unroll
    for (int q = 0; q < 3; ++q) acc[mi][q] = {0.f, 0.f, 0.f, 0.f};

  auto loadB = [&](int c) -> B3 {
    const short* bb = w0f + ((size_t)c * 12 + wn * 3) * 1024 + lane * 8;
    B3 b;
    b.b0 = *(const short8*)(bb);
    b.b1 = *(const short8*)(bb + 1024);
    b.b2 = *(const short8*)(bb + 2048);
    return b;
  };

  auto write_feats_ss = [&](int buf, int c) {
    const unsigned mv = *(const unsigned*)(mss + c*32 + 2*kp);
    const int u0 = (mv >> 8) & 255,  v0 = mv & 255;
    const int u1 = (mv >> 24) & 255, v1i = (mv >> 16) & 255;
    char* a0 = (char*)&sA[buf][0];
    #pragma unroll
    for (int i = 0; i < 2; ++i) {
      const int m = rg*2 + i;
      const float* sr = &sSV[m*129];
      float f0 = sr[u0] * sr[v0];
      float f1 = sr[u1] * sr[v1i];
      const int off = m*64 + (((kp>>2) ^ ((m>>1)&3)) << 4) + ((kp&3) << 2);
      *(unsigned*)(a0 + off) = cvt_pk_bf16(f0, f1);
    }
  };
  auto write_feats_dd = [&](int buf, int c) {
    const unsigned mv = *(const unsigned*)(mdd + (c - NCH_SS)*32 + 2*kp);
    const int u0 = (mv >> 8) & 255,  v0 = mv & 255;
    const int u1 = (mv >> 24) & 255, v1i = (mv >> 16) & 255;
    char* a0 = (char*)&sA[buf][0];
    #pragma unroll
    for (int i = 0; i < 2; ++i) {
      const int m = rg*2 + i;
      const float* vr = &sSV[m*193];
      const float* pa0 = vr + u0*3; const float* pb0 = vr + v0*3;
      const float* pa1 = vr + u1*3; const float* pb1 = vr + v1i*3;
      float f0 = (pa0[0]*pb0[0] + pa0[1]*pb0[1] + pa0[2]*pb0[2]) * INV_SQRT3;
      float f1 = (pa1[0]*pb1[0] + pa1[1]*pb1[1] + pa1[2]*pb1[2]) * INV_SQRT3;
      const int off = m*64 + (((kp>>2) ^ ((m>>1)&3)) << 4) + ((kp&3) << 2);
      *(unsigned*)(a0 + off) = cvt_pk_bf16(f0, f1);
    }
  };

  auto mfma_step = [&](const B3& B, int buf) {
    #pragma unroll
    for (int mi = 0; mi < 2; ++mi) {
      const int m = mi*16 + (lane & 15);
      const int kg = lane >> 4;
      const int off = m*64 + ((kg ^ ((m>>1)&3)) << 4);
      short8 ah = *(const short8*)((const char*)&sA[buf][0] + off);
      acc[mi][0] = __builtin_amdgcn_mfma_f32_16x16x32_bf16(ah, B.b0, acc[mi][0], 0, 0, 0);
      acc[mi][1] = __builtin_amdgcn_mfma_f32_16x16x32_bf16(ah, B.b1, acc[mi][1], 0, 0, 0);
      acc[mi][2] = __builtin_amdgcn_mfma_f32_16x16x32_bf16(ah, B.b2, acc[mi][2], 0, 0, 0);
    }
  };

  __syncthreads();

  B3 Ba = loadB(0), Bb;
  write_feats_ss(0, 0);
  __syncthreads();
  for (int c = 0; c < NCH_SS; c += 2) {
    Bb = loadB(c + 1);
    write_feats_ss(1, c + 1);
    mfma_step(Ba, 0);
    __syncthreads();
    if (c + 2 < NCH_SS) { Ba = loadB(c + 2); write_feats_ss(0, c + 2); }
    mfma_step(Bb, 1);
    __syncthreads();
  }

  for (int i = tid; i < 32*192; i += 256) {
    int r = i / 192, c = i - r*192;
    sSV[r*193 + c] = v1[(size_t)(r0 + r)*192 + c];
  }
  __syncthreads();

  Ba = loadB(NCH_SS);
  write_feats_dd(0, NCH_SS);
  __syncthreads();
  for (int c = NCH_SS; c < NCH; c += 2) {
    const bool has1 = (c + 1 < NCH);
    if (has1) { Bb = loadB(c + 1); write_feats_dd(1, c + 1); }
    mfma_step(Ba, 0);
    __syncthreads();
    if (has1) {
      if (c + 2 < NCH) { Ba = loadB(c + 2); write_feats_dd(0, c + 2); }
      mfma_step(Bb, 1);
      __syncthreads();
    }
  }

  const float nrm = 1.0f / sqrtf((float)P0_2);
  #pragma unroll
  for (int mi = 0; mi < 2; ++mi) {
    const int rowbase = r0 + mi*16 + (lane >> 4)*4;
    #pragma unroll
    for (int q = 0; q < 3; ++q) {
      const int col = (wn*3 + q)*16 + (lane & 15);
      #pragma unroll
      for (int r = 0; r < 4; ++r) {
        float val = acc[mi][q][r] * nrm;
        float sg = 1.f / (1.f + __expf(-val));
        if (col < N0H) s2[(size_t)(rowbase + r)*N0H + col] = val * sg;
        else           g2[(size_t)(rowbase + r)*N1H + (col - N0H)] = sg;
      }
    }
  }
}

// ---------------- layer 2 vector path: B hi-only + VGPR-double-buffered B (R12) ----------------
__global__ __launch_bounds__(256, 5) void k_l2_vector_f(
    const float* __restrict__ s1, const float* __restrict__ v1,
    const short* __restrict__ w1f,
    const float* __restrict__ g2,
    float* __restrict__ v2)
{
  __shared__ float sS[16*129];
  __shared__ float sV[16*193];
  __shared__ float sG[16*66];
  __shared__ __align__(16) short sA[2][1536];

  const int tid = threadIdx.x, lane = tid & 63, wid = tid >> 6;
  const int wn = wid;
  const int n0 = blockIdx.x * 16;
  const int kp = tid & 15, rg = tid >> 4;

  for (int i = tid; i < 16*128; i += 256) {
    int n = i >> 7, c = i & 127;
    sS[n*129 + c] = s1[(size_t)(n0 + n)*128 + c];
  }
  for (int i = tid; i < 16*192; i += 256) {
    int n = i / 192, c = i - n*192;
    sV[n*193 + c] = v1[(size_t)(n0 + n)*192 + c];
  }
  for (int i = tid; i < 16*64; i += 256) {
    int n = i >> 6, c = i & 63;
    sG[n*66 + c] = g2[(size_t)(n0 + n)*64 + c];
  }

  f32x4 acc[3];
  #pragma unroll
  for (int mi = 0; mi < 3; ++mi) acc[mi] = {0.f, 0.f, 0.f, 0.f};

  auto loadB = [&](int c) -> short8 {
    return *(const short8*)(w1f + ((size_t)c * 4 + wn) * 1024 + lane * 8);
  };

  auto gen = [&](int buf, int c) {
    const int u = c >> 1;
    const int w0 = (c & 1) * 32 + 2*kp;
    char* a0 = (char*)&sA[buf][0];
    const float sval = sS[rg*129 + u];
    #pragma unroll
    for (int i3 = 0; i3 < 3; ++i3) {
      const int row = rg*3 + i3;
      const float f0 = sval * sV[rg*193 + w0*3 + i3];
      const float f1 = sval * sV[rg*193 + (w0+1)*3 + i3];
      const int off = row*64 + (((kp>>2) ^ ((row>>1)&3)) << 4) + ((kp&3) << 2);
      *(unsigned*)(a0 + off) = cvt_pk_bf16(f0, f1);
    }
  };

  auto mfma_step = [&](short8 bh, int buf) {
    const int c15 = lane & 15, kg = lane >> 4;
    #pragma unroll
    for (int mi = 0; mi < 3; ++mi) {
      const int row = mi*16 + c15;
      const int off = row*64 + ((kg ^ ((row>>1)&3)) << 4);
      short8 ah = *(const short8*)((const char*)&sA[buf][0] + off);
      acc[mi] = __builtin_amdgcn_mfma_f32_16x16x32_bf16(ah, bh, acc[mi], 0, 0, 0);
    }
  };

  __syncthreads();
  short8 Ba = loadB(0), Bb;
  gen(0, 0);
  __syncthreads();
  for (int c = 0; c < NCH1; c += 2) {
    Bb = loadB(c + 1);
    gen(1, c + 1);
    mfma_step(Ba, 0);
    __syncthreads();
    if (c + 2 < NCH1) { Ba = loadB(c + 2); gen(0, c + 2); }
    mfma_step(Bb, 1);
    __syncthreads();
  }

  const float nrm = 1.0f / sqrtf((float)P1_2);
  const int c15 = lane & 15, lg = lane >> 4;
  #pragma unroll
  for (int mi = 0; mi < 3; ++mi) {
    const int m = wn*16 + c15;
    #pragma unroll
    for (int r = 0; r < 4; ++r) {
      const int row = mi*16 + lg*4 + r;
      const int n = row / 3, i3 = row - n*3;
      const float g = sG[n*66 + m] * nrm;
      v2[(size_t)(n0 + n)*192 + m*3 + i3] = acc[mi][r] * g;
    }
  }
}

// ---------------- final: MFMA quadratic forms (validated R12) ----------------
__global__ __launch_bounds__(256) void k_final_mfma(
    const float* __restrict__ s2, const float* __restrict__ v2,
    const short* __restrict__ wfm, const short* __restrict__ wfd,
    float* __restrict__ out)
{
  __shared__ float sS2[32*129];
  __shared__ float sV2[32*193];
  __shared__ __align__(16) short sAS[4][1024];
  __shared__ __align__(16) short sAD[2][3072];
  __shared__ float psumS[32][5];
  __shared__ float psumD[96][5];

  const int tid = threadIdx.x, lane = tid & 63, wid = tid >> 6;
  const int n0 = blockIdx.x * 32;
  const int kp = tid & 15, rg = tid >> 4;
  const int c15 = lane & 15, lg = lane >> 4;

  for (int i = tid; i < 32*128; i += 256) {
    int n = i >> 7, c = i & 127;
    sS2[n*129 + c] = s2[(size_t)(n0 + n)*128 + c];
  }
  for (int i = tid; i < 32*192; i += 256) {
    int n = i / 192, c = i - n*192;
    sV2[n*193 + c] = v2[(size_t)(n0 + n)*192 + c];
  }
  __syncthreads();

  #pragma unroll
  for (int c = 0; c < 4; ++c) {
    char* a0 = (char*)&sAS[c][0];
    #pragma unroll
    for (int i = 0; i < 2; ++i) {
      const int m = rg*2 + i;
      float f0 = sS2[m*129 + c*32 + 2*kp];
      float f1 = sS2[m*129 + c*32 + 2*kp + 1];
      const int off = m*64 + (((kp>>2) ^ ((m>>1)&3)) << 4) + ((kp&3) << 2);
      *(unsigned*)(a0 + off) = cvt_pk_bf16(f0, f1);
    }
  }
  #pragma unroll
  for (int c = 0; c < 2; ++c) {
    char* a0 = (char*)&sAD[c][0];
    #pragma unroll
    for (int rr = 0; rr < 6; ++rr) {
      const int row = rg*6 + rr;
      const int n = rg*2 + rr/3, i3 = rr % 3;
      const int w0 = c*32 + 2*kp;
      float f0 = sV2[n*193 + w0*3 + i3];
      float f1 = sV2[n*193 + (w0+1)*3 + i3];
      const int off = row*64 + (((kp>>2) ^ ((row>>1)&3)) << 4) + ((kp&3) << 2);
      *(unsigned*)(a0 + off) = cvt_pk_bf16(f0, f1);
    }
  }
  __syncthreads();

  f32x4 accS[2][2];
  #pragma unroll
  for (int mi = 0; mi < 2; ++mi)
    #pragma unroll
    for (int q = 0; q < 2; ++q) accS[mi][q] = {0.f, 0.f, 0.f, 0.f};
  #pragma unroll
  for (int c = 0; c < 4; ++c) {
    #pragma unroll
    for (int q = 0; q < 2; ++q) {
      const short* bb = wfm + ((size_t)(c*8 + wid*2 + q))*1024 + lane*8;
      short8 bh = *(const short8*)(bb);
      short8 bl = *(const short8*)(bb + 512);
      #pragma unroll
      for (int mi = 0; mi < 2; ++mi) {
        const int row = mi*16 + c15;
        const int off = row*64 + ((lg ^ ((row>>1)&3)) << 4);
        short8 ah = *(const short8*)((const char*)&sAS[c][0] + off);
        accS[mi][q] = __builtin_amdgcn_mfma_f32_16x16x32_bf16(ah, bh, accS[mi][q], 0, 0, 0);
        accS[mi][q] = __builtin_amdgcn_mfma_f32_16x16x32_bf16(ah, bl, accS[mi][q], 0, 0, 0);
      }
    }
  }

  f32x4 accD[6];
  #pragma unroll
  for (int mi = 0; mi < 6; ++mi) accD[mi] = {0.f, 0.f, 0.f, 0.f};
  #pragma unroll
  for (int c = 0; c < 2; ++c) {
    const short* bb = wfd + ((size_t)(c*4 + wid))*1024 + lane*8;
    short8 bh = *(const short8*)(bb);
    short8 bl = *(const short8*)(bb + 512);
    #pragma unroll
    for (int mi = 0; mi < 6; ++mi) {
      const int row = mi*16 + c15;
      const int off = row*64 + ((lg ^ ((row>>1)&3)) << 4);
      short8 ah = *(const short8*)((const char*)&sAD[c][0] + off);
      accD[mi] = __builtin_amdgcn_mfma_f32_16x16x32_bf16(ah, bh, accD[mi], 0, 0, 0);
      accD[mi] = __builtin_amdgcn_mfma_f32_16x16x32_bf16(ah, bl, accD[mi], 0, 0, 0);
    }
  }

  #pragma unroll
  for (int mi = 0; mi < 2; ++mi) {
    #pragma unroll
    for (int r = 0; r < 4; ++r) {
      const int row = mi*16 + lg*4 + r;
      float p = 0.f;
      #pragma unroll
      for (int q = 0; q < 2; ++q) {
        const int col = (wid*2 + q)*16 + c15;
        p += accS[mi][q][r] * sS2[row*129 + col];
      }
      #pragma unroll
      for (int off = 1; off < 16; off <<= 1) p += __shfl_xor(p, off, 16);
      if (c15 == 0) psumS[row][wid] = p;
    }
  }
  #pragma unroll
  for (int mi = 0; mi < 6; ++mi) {
    #pragma unroll
    for (int r = 0; r < 4; ++r) {
      const int row = mi*16 + lg*4 + r;
      const int n = row / 3, i3 = row - n*3;
      const int col = wid*16 + c15;
      float p = accD[mi][r] * sV2[n*193 + col*3 + i3];
      #pragma unroll
      for (int off = 1; off < 16; off <<= 1) p += __shfl_xor(p, off, 16);
      if (c15 == 0) psumD[row][wid] = p;
    }
  }
  __syncthreads();

  if (tid < 32) {
    float s = 0.f;
    #pragma unroll
    for (int w = 0; w < 4; ++w) s += psumS[tid][w];
    #pragma unroll
    for (int j = 0; j < 3; ++j)
      #pragma unroll
      for (int w = 0; w < 4; ++w) s += psumD[tid*3 + j][w];
    out[n0 + tid] = s * (1.0f / sqrtf((float)P0_2));
  }
}

// ---------------- launch ----------------
extern "C" void kernel_launch(void* const* d_in, const int* in_sizes, int n_in,
                              void* d_out, int out_size, void* d_ws, size_t ws_size,
                              hipStream_t stream)
{
  const float* x    = (const float*)d_in[0];
  const float* w0_1 = (const float*)d_in[1];
  const float* w1_1 = (const float*)d_in[2];
  const float* w0_2 = (const float*)d_in[3];
  const float* w1_2 = (const float*)d_in[4];
  const float* w0_f = (const float*)d_in[5];
  float* out = (float*)d_out;
  char* ws = (char*)d_ws;

  if (ws_size < WS_NEED) return;

  u16* mss2 = (u16*)(ws + O_MSS2);
  u16* mdd2 = (u16*)(ws + O_MDD2);
  u16* mc1  = (u16*)(ws + O_MC1);
  short* w01f = (short*)(ws + O_W01F);
  short* w11f = (short*)(ws + O_W11F);
  short* w0f  = (short*)(ws + O_W0F);
  short* w1f  = (short*)(ws + O_W1F);
  short* wfm  = (short*)(ws + O_WFM);
  short* wfd  = (short*)(ws + O_WFD);
  float* s1 = (float*)(ws + O_S1);
  float* v1 = (float*)(ws + O_V1);
  float* s2 = (float*)(ws + O_S2);
  float* g1 = (float*)(ws + O_G1);
  float* g2 = (float*)(ws + O_G2);
  float* v2 = (float*)(ws + O_V2);

  hipLaunchKernelGGL(k_init_maps, dim3(1), dim3(128), 0, stream, mss2, mdd2, mc1);
  hipLaunchKernelGGL(k_prep_b01, dim3((NCH_L1*12 + 3)/4), dim3(256), 0, stream, w0_1, w01f);
  hipLaunchKernelGGL(k_prep_b11, dim3(NCH_V1), dim3(256), 0, stream, w1_1, w11f);
  hipLaunchKernelGGL(k_prep_b, dim3((NCH*12 + 3)/4), dim3(256), 0, stream, w0_2, w0f);
  hipLaunchKernelGGL(k_prep_b1v, dim3(NCH1), dim3(256), 0, stream, w1_2, w1f);
  hipLaunchKernelGGL(k_prep_wfm, dim3(8), dim3(256), 0, stream, w0_f, wfm);
  hipLaunchKernelGGL(k_prep_wfd, dim3(2), dim3(256), 0, stream, w0_f, wfd);
  hipLaunchKernelGGL(k_layer1s_mfma, dim3(NR/64), dim3(256), 0, stream,
                     x, w01f, mc1, s1, g1);
  hipLaunchKernelGGL(k_layer1v_f, dim3(NR/32), dim3(256), 0, stream,
                     x, w11f, g1, v1);
  hipLaunchKernelGGL(k_l2_scalar_mfma, dim3(NR/32), dim3(256), 0, stream,
                     s1, v1, w0f, mss2, mdd2, s2, g2);
  hipLaunchKernelGGL(k_l2_vector_f, dim3(NR/16), dim3(256), 0, stream,
                     s1, v1, w1f, g2, v2);
  hipLaunchKernelGGL(k_final_mfma, dim3(NR/32), dim3(256), 0, stream,
                     s2, v2, wfm, wfd, out);
}